// Round 9
// baseline (554.108 us; speedup 1.0000x reference)
//
#include <hip/hip_runtime.h>
#include <hip/hip_bf16.h>

// RGCN encoder: N=100000, E=128, R=9, L=3, NE=640000. Only the LAST layer
// matters (reference resets hidden=embeddings each layer).
//   out[n] = sum_{e:dst=n}(W_t h[src]+b_t) + sum_{e:src=n}(W_{t+9} h[dst]+b_{t+9})
// AGGREGATE-FIRST rewrite (linearity): out[d] = sum_t W_t * M_t[d] + deg_t(d)*b_t
// where M_t[d] = sum of h[other] over type-t edges into d. This deletes the
// 460MB ht materialization + 328MB random gather of rounds 2-8 entirely.
//  (1) h_to_bf: emb -> bf16 Hbf (25.6MB, L2/L3-resident gather source)
//  (2) CSR at (node,type) granularity: 18*Nn segments, octant-partitioned
//      count/fill + hierarchical scan -> records grouped by type per node
//  (3) fused_rgcn: 16 nodes/block; per direction: aggregate type-runs from
//      Hbf into LDS Mt[16][1152] (fp32 regs, exact; empty runs write zeros),
//      then MFMA out_tile += Mt @ Wcat (K=1152, swapped operands r7/r8-style);
//      epilogue adds deg_t*b_t and stores out once. No atomics anywhere.

#define E_DIM 128
#define R_REL 9
#define TN 16        // nodes per fused block
#define MT_P 1156    // Mt pitch (ushorts): 2312B rows -> bank stride 2, b128-min
#define SCB 1024     // elements per scan block
#define NSLICE 96    // edge slices per octant in count/fill

typedef __attribute__((ext_vector_type(8))) short short8v;
typedef __attribute__((ext_vector_type(4))) float f32x4;

static __device__ __forceinline__ unsigned short f2bf(float f) {
    union { float f; unsigned u; } v; v.f = f;
    unsigned u = v.u;
    return (unsigned short)((u + 0x7FFFu + ((u >> 16) & 1u)) >> 16);
}
static __device__ __forceinline__ float bf2f(unsigned short h) {
    union { unsigned u; float f; } v; v.u = ((unsigned)h) << 16;
    return v.f;
}

// ---------- fast path ----------

__global__ __launch_bounds__(256) void h_to_bf(
    const float* __restrict__ H, unsigned short* __restrict__ Hbf, long total8)
{
    long i = (long)blockIdx.x * 256 + threadIdx.x;
    if (i >= total8) return;
    const float4* src = (const float4*)(H + i * 8);
    float4 a = src[0], b = src[1];
    short8v o;
    o[0] = (short)f2bf(a.x); o[1] = (short)f2bf(a.y);
    o[2] = (short)f2bf(a.z); o[3] = (short)f2bf(a.w);
    o[4] = (short)f2bf(b.x); o[5] = (short)f2bf(b.y);
    o[6] = (short)f2bf(b.z); o[7] = (short)f2bf(b.w);
    *(short8v*)(Hbf + i * 8) = o;
}

// Wt[rel][w][s][c][lane][j] = bf16(W[rel][k=s*32+(lane>>4)*8+j][col=w*32+c*16+(lane&15)])
__global__ __launch_bounds__(256) void w_swizzle(
    const float* __restrict__ W18, unsigned short* __restrict__ Wt)
{
    const int rel = blockIdx.x;
    const float* __restrict__ Wr = W18 + (size_t)rel * E_DIM * E_DIM;
    const int tid = threadIdx.x;
#pragma unroll
    for (int k = 0; k < 8; k++) {
        int f = tid + k * 256;            // 0..2047
        int lane = f & 63;
        int c = (f >> 6) & 1;
        int s = (f >> 7) & 3;
        int w = (f >> 9) & 3;
        int col = w * 32 + c * 16 + (lane & 15);
        int kb = s * 32 + (lane >> 4) * 8;
        short8v v;
#pragma unroll
        for (int j = 0; j < 8; j++)
            v[j] = (short)f2bf(Wr[(size_t)(kb + j) * E_DIM + col]);
        *(short8v*)(Wt + ((size_t)((((rel * 4 + w) * 4 + s) * 2 + c) * 64 + lane)) * 8) = v;
    }
}

// CSR over n3 = 18*Nn segments, key = seg*9 + t where seg = d (fwd) or Nn+s (bwd).
// Octant-partitioned by node for XCD-L2-local counters.
__global__ __launch_bounds__(256) void k_count8(
    const int* __restrict__ esrc, const int* __restrict__ edst,
    const int* __restrict__ etype, int* __restrict__ cnt, int ne, int Nn)
{
    const int oct = blockIdx.x & 7;
    const int slice = blockIdx.x >> 3;
    const int lo = (int)(((long long)oct * Nn) >> 3);
    const int hi = (int)(((long long)(oct + 1) * Nn) >> 3);
    for (int e = slice * 256 + threadIdx.x; e < ne; e += NSLICE * 256) {
        int t = etype[e], s = esrc[e], d = edst[e];
        if (d >= lo && d < hi) atomicAdd(&cnt[d * R_REL + t], 1);
        if (s >= lo && s < hi) atomicAdd(&cnt[(Nn + s) * R_REL + t], 1);
    }
}

// Hierarchical scan, 3 kernels.
__global__ __launch_bounds__(256) void k_scan_part(
    const int* __restrict__ cnt, int* __restrict__ loc,
    int* __restrict__ bsum, int n2)
{
    __shared__ int sh[256];
    const int tid = threadIdx.x;
    const int i0 = blockIdx.x * SCB + tid * 4;
    int v0 = 0, v1 = 0, v2 = 0, v3 = 0;
    if (i0 + 3 < n2) {
        int4 v = *(const int4*)(cnt + i0);
        v0 = v.x; v1 = v.y; v2 = v.z; v3 = v.w;
    } else {
        if (i0 + 0 < n2) v0 = cnt[i0 + 0];
        if (i0 + 1 < n2) v1 = cnt[i0 + 1];
        if (i0 + 2 < n2) v2 = cnt[i0 + 2];
        if (i0 + 3 < n2) v3 = cnt[i0 + 3];
    }
    int t = v0 + v1 + v2 + v3;
    sh[tid] = t;
    __syncthreads();
    for (int o = 1; o < 256; o <<= 1) {
        int x = (tid >= o) ? sh[tid - o] : 0;
        __syncthreads();
        sh[tid] += x;
        __syncthreads();
    }
    int excl = sh[tid] - t;
    if (tid == 255) bsum[blockIdx.x] = sh[255];
    int p0 = excl, p1 = p0 + v0, p2 = p1 + v1, p3 = p2 + v2;
    if (i0 + 3 < n2) {
        *(int4*)(loc + i0) = make_int4(p0, p1, p2, p3);
    } else {
        if (i0 + 0 < n2) loc[i0 + 0] = p0;
        if (i0 + 1 < n2) loc[i0 + 1] = p1;
        if (i0 + 2 < n2) loc[i0 + 2] = p2;
        if (i0 + 3 < n2) loc[i0 + 3] = p3;
    }
}

__global__ __launch_bounds__(256) void k_scan_mid(int* __restrict__ bsum, int nb)
{
    __shared__ int sh[256];
    __shared__ int carry;
    const int tid = threadIdx.x;
    if (tid == 0) carry = 0;
    __syncthreads();
    for (int base = 0; base < nb; base += 256) {
        int i = base + tid;
        int v = (i < nb) ? bsum[i] : 0;
        sh[tid] = v;
        __syncthreads();
        for (int o = 1; o < 256; o <<= 1) {
            int x = (tid >= o) ? sh[tid - o] : 0;
            __syncthreads();
            sh[tid] += x;
            __syncthreads();
        }
        int excl = sh[tid] - v + carry;
        int total = sh[255];
        if (i < nb) bsum[i] = excl;
        __syncthreads();
        if (tid == 0) carry += total;
        __syncthreads();
    }
}

__global__ __launch_bounds__(256) void k_scan_apply(
    const int* __restrict__ loc, const int* __restrict__ bsum,
    int* __restrict__ off, int* __restrict__ cursor, int n2)
{
    const int add = bsum[blockIdx.x];
    const int i0 = blockIdx.x * SCB + threadIdx.x * 4;
    if (i0 + 3 < n2) {
        int4 v = *(const int4*)(loc + i0);
        v.x += add; v.y += add; v.z += add; v.w += add;
        *(int4*)(off + i0) = v;
        *(int4*)(cursor + i0) = v;
    } else {
#pragma unroll
        for (int j = 0; j < 4; j++)
            if (i0 + j < n2) {
                int v = loc[i0 + j] + add;
                off[i0 + j] = v;
                cursor[i0 + j] = v;
            }
    }
}

// rec value = other node id (type implicit in segment key).
__global__ __launch_bounds__(256) void k_fill8(
    const int* __restrict__ esrc, const int* __restrict__ edst,
    const int* __restrict__ etype, int* __restrict__ cursor,
    unsigned* __restrict__ rec, int ne, int Nn)
{
    const int oct = blockIdx.x & 7;
    const int slice = blockIdx.x >> 3;
    const int lo = (int)(((long long)oct * Nn) >> 3);
    const int hi = (int)(((long long)(oct + 1) * Nn) >> 3);
    for (int e = slice * 256 + threadIdx.x; e < ne; e += NSLICE * 256) {
        int t = etype[e], s = esrc[e], d = edst[e];
        if (d >= lo && d < hi) {
            int p = atomicAdd(&cursor[d * R_REL + t], 1);
            rec[p] = (unsigned)s;                    // fwd msg into d
        }
        if (s >= lo && s < hi) {
            int p2 = atomicAdd(&cursor[(Nn + s) * R_REL + t], 1);
            rec[p2] = (unsigned)d;                   // bwd msg into s
        }
    }
}

// Fused aggregate+GEMM. Block = 16 nodes, 4 waves. Per direction:
//   each wave aggregates 4 nodes: for t in 0..8, sum Hbf rows of the
//   (node,t) run in fp32 regs (lane = 2 channels), flush bf16 to Mt[node]
//   (empty runs flush zeros); barrier; MFMA out_tile += Mt @ Wcat
//   (swapped operands: lane&15 = node, acc reg = 4 consecutive cols).
// Epilogue: + deg_t * b_t per direction, single fp32 out store.
__global__ __launch_bounds__(256, 4) void fused_rgcn(
    const unsigned short* __restrict__ Hbf, const unsigned short* __restrict__ Wt,
    const float* __restrict__ B18,
    const int* __restrict__ off2, const int* __restrict__ cur2,
    const unsigned* __restrict__ rec,
    float* __restrict__ out, int Nn)
{
    __shared__ __align__(16) unsigned short Mt[TN][MT_P];
    __shared__ float degS[2][TN][R_REL];

    const int tid = threadIdx.x;
    const int lane = tid & 63;
    const int w = tid >> 6;             // wave id; col slice w*32..w*32+31
    const int lr = lane & 15;
    const int lg = lane >> 4;
    const int n0 = blockIdx.x * TN;

    const short8v* wt8 = (const short8v*)Wt;

    f32x4 acc[2];
    acc[0] = (f32x4){0.f, 0.f, 0.f, 0.f};
    acc[1] = (f32x4){0.f, 0.f, 0.f, 0.f};

#pragma unroll 1
    for (int dir = 0; dir < 2; dir++) {
        // ---- aggregation: wave w owns nodes w*4 .. w*4+3 ----
#pragma unroll 1
        for (int j = 0; j < 4; j++) {
            const int node = w * 4 + j;
            const int gnode = n0 + node;
            // Segment bounds for all 9 types via one lane-spread load + shfl.
            int bnd = 0;
            if (gnode < Nn) {
                size_t segbase = (size_t)(dir ? (Nn + gnode) : gnode) * R_REL;
                if (lane < R_REL)       bnd = off2[segbase + lane];
                else if (lane == R_REL) bnd = cur2[segbase + R_REL - 1];
            }
#pragma unroll 1
            for (int t = 0; t < R_REL; t++) {
                int st = __shfl(bnd, t);
                int en = __shfl(bnd, t + 1);
                float a0 = 0.f, a1 = 0.f;
                int i = st;
                for (; i + 2 <= en; i += 2) {
                    unsigned r0 = rec[i], r1 = rec[i + 1];
                    ushort2 v0 = *(const ushort2*)(Hbf + (size_t)r0 * E_DIM + 2 * lane);
                    ushort2 v1 = *(const ushort2*)(Hbf + (size_t)r1 * E_DIM + 2 * lane);
                    a0 += bf2f(v0.x) + bf2f(v1.x);
                    a1 += bf2f(v0.y) + bf2f(v1.y);
                }
                if (i < en) {
                    unsigned r0 = rec[i];
                    ushort2 v0 = *(const ushort2*)(Hbf + (size_t)r0 * E_DIM + 2 * lane);
                    a0 += bf2f(v0.x);
                    a1 += bf2f(v0.y);
                }
                unsigned pk = ((unsigned)f2bf(a1) << 16) | (unsigned)f2bf(a0);
                *(unsigned*)((char*)&Mt[node][t * E_DIM] + lane * 4) = pk;
                if (lane == 0) degS[dir][node][t] = (float)(en - st);
            }
        }
        __syncthreads();

        // ---- GEMM: acc += Mt @ W[dir group] ----
#pragma unroll 1
        for (int q = 0; q < R_REL; q++) {
            const int rel = dir * R_REL + q;
#pragma unroll
            for (int s = 0; s < 4; s++) {
                short8v b0 = wt8[(size_t)((((rel * 4 + w) * 4 + s) * 2 + 0) * 64) + lane];
                short8v b1 = wt8[(size_t)((((rel * 4 + w) * 4 + s) * 2 + 1) * 64) + lane];
                short8v a = *(const short8v*)(&Mt[lr][q * E_DIM + s * 32 + lg * 8]);
                acc[0] = __builtin_amdgcn_mfma_f32_16x16x32_bf16(b0, a, acc[0], 0, 0, 0);
                acc[1] = __builtin_amdgcn_mfma_f32_16x16x32_bf16(b1, a, acc[1], 0, 0, 0);
            }
        }
        __syncthreads();   // before next dir overwrites Mt
    }

    // ---- epilogue: bias (deg_t * b_t) + store ----
    const int gnode = n0 + lr;
    if (gnode >= Nn) return;
#pragma unroll 1
    for (int dir = 0; dir < 2; dir++) {
#pragma unroll 1
        for (int t = 0; t < R_REL; t++) {
            float dg = degS[dir][lr][t];
            if (dg != 0.f) {
                const float* brow = B18 + (size_t)(dir * R_REL + t) * E_DIM + w * 32 + lg * 4;
                float4 b0 = *(const float4*)(brow);
                float4 b1 = *(const float4*)(brow + 16);
                acc[0][0] += dg * b0.x; acc[0][1] += dg * b0.y;
                acc[0][2] += dg * b0.z; acc[0][3] += dg * b0.w;
                acc[1][0] += dg * b1.x; acc[1][1] += dg * b1.y;
                acc[1][2] += dg * b1.z; acc[1][3] += dg * b1.w;
            }
        }
    }
    float* po = out + (size_t)gnode * E_DIM + w * 32 + lg * 4;
    *(float4*)po = make_float4(acc[0][0], acc[0][1], acc[0][2], acc[0][3]);
    *(float4*)(po + 16) = make_float4(acc[1][0], acc[1][1], acc[1][2], acc[1][3]);
}

// ---------- zero-workspace fallback (round-1, validated) ----------

__global__ __launch_bounds__(128) void direct_edge(
    const int* __restrict__ esrc, const int* __restrict__ edst,
    const int* __restrict__ etype,
    const float* __restrict__ H, const float* __restrict__ W2,
    const float* __restrict__ B2, float* __restrict__ out, int ne)
{
    __shared__ float hs[E_DIM];
    __shared__ float hd[E_DIM];
    int e = blockIdx.x;
    if (e >= ne) return;
    int t = etype[e], s = esrc[e], d = edst[e];
    int c = threadIdx.x;
    hs[c] = H[(size_t)s * E_DIM + c];
    hd[c] = H[(size_t)d * E_DIM + c];
    __syncthreads();
    const float* Wf = W2 + (size_t)t * E_DIM * E_DIM;
    const float* Wb = W2 + (size_t)(t + R_REL) * E_DIM * E_DIM;
    float accf = B2[(size_t)t * E_DIM + c];
    float accb = B2[(size_t)(t + R_REL) * E_DIM + c];
#pragma unroll 8
    for (int k = 0; k < E_DIM; k++) {
        accf += hs[k] * Wf[(size_t)k * E_DIM + c];
        accb += hd[k] * Wb[(size_t)k * E_DIM + c];
    }
    atomicAdd(&out[(size_t)d * E_DIM + c], accf);
    atomicAdd(&out[(size_t)s * E_DIM + c], accb);
}

extern "C" void kernel_launch(void* const* d_in, const int* in_sizes, int n_in,
                              void* d_out, int out_size, void* d_ws, size_t ws_size,
                              hipStream_t stream) {
    const int* edge_index = (const int*)d_in[0];   // [2][NE]
    const int* edge_type  = (const int*)d_in[1];   // [NE]
    const float* emb      = (const float*)d_in[2]; // [N][128]
    const float* weights  = (const float*)d_in[3]; // [L][18][128][128]
    const float* biases   = (const float*)d_in[4]; // [L][18][128]
    float* out = (float*)d_out;

    const int NE = in_sizes[1];
    const int Nn = in_sizes[2] / E_DIM;
    const int L  = in_sizes[3] / (2 * R_REL * E_DIM * E_DIM);

    const float* W2 = weights + (size_t)(L - 1) * 2 * R_REL * E_DIM * E_DIM;
    const float* B2 = biases  + (size_t)(L - 1) * 2 * R_REL * E_DIM;

    const int* esrc = edge_index;
    const int* edst = edge_index + NE;

    const int n3 = 2 * Nn * R_REL;                 // (node,type) segments
    const int nb3 = (n3 + SCB - 1) / SCB;

    auto al = [](size_t x) { return (x + 255) & ~(size_t)255; };
    const size_t hbfBytes = al((size_t)Nn * E_DIM * 2);
    const size_t wtBytes  = al((size_t)2 * R_REL * E_DIM * E_DIM * 2);
    const size_t offBytes = al((size_t)n3 * 4);
    const size_t curBytes = al((size_t)n3 * 4);
    const size_t recBytes = al((size_t)2 * NE * 4);
    const size_t bsBytes  = al((size_t)nb3 * 4);
    const size_t need = hbfBytes + wtBytes + offBytes + curBytes + recBytes + bsBytes;

    if (ws_size >= need) {
        char* p = (char*)d_ws;
        unsigned short* Hbf = (unsigned short*)p;        p += hbfBytes;
        unsigned short* Wt  = (unsigned short*)p;        p += wtBytes;
        int* off2           = (int*)p;                   p += offBytes;
        int* cur2           = (int*)p;                   p += curBytes;
        unsigned* rec       = (unsigned*)p;              p += recBytes;
        int* bsum           = (int*)p;

        const long total8 = (long)Nn * (E_DIM / 8);
        h_to_bf<<<(int)((total8 + 255) / 256), 256, 0, stream>>>(emb, Hbf, total8);
        w_swizzle<<<2 * R_REL, 256, 0, stream>>>(W2, Wt);

        hipMemsetAsync(off2, 0, (size_t)n3 * 4, stream);
        k_count8<<<8 * NSLICE, 256, 0, stream>>>(esrc, edst, edge_type, off2, NE, Nn);
        k_scan_part<<<nb3, 256, 0, stream>>>(off2, cur2, bsum, n3);
        k_scan_mid<<<1, 256, 0, stream>>>(bsum, nb3);
        k_scan_apply<<<nb3, 256, 0, stream>>>(cur2, bsum, off2, cur2, n3);
        k_fill8<<<8 * NSLICE, 256, 0, stream>>>(esrc, edst, edge_type,
                                                cur2, rec, NE, Nn);

        fused_rgcn<<<(Nn + TN - 1) / TN, 256, 0, stream>>>(
            Hbf, Wt, B2, off2, cur2, rec, out, Nn);
        return;
    }

    // Fallback: direct per-edge GEMV with atomics.
    hipMemsetAsync(d_out, 0, (size_t)Nn * E_DIM * sizeof(float), stream);
    direct_edge<<<NE, 128, 0, stream>>>(esrc, edst, edge_type, emb, W2, B2, out, NE);
}

// Round 10
// 449.001 us; speedup vs baseline: 1.2341x; 1.2341x over previous
//
#include <hip/hip_runtime.h>
#include <hip/hip_bf16.h>

// RGCN encoder: N=100000, E=128, R=9, L=3, NE=640000. Only the LAST layer
// matters (reference resets hidden=embeddings each layer).
//   out[n] = sum_{e:dst=n}(W_t h[src]+b_t) + sum_{e:src=n}(W_{t+9} h[dst]+b_{t+9})
// AGGREGATE-FIRST (linearity): out[d] = sum_t W_t * M_t[d] + deg_t(d)*b_t,
// M_t[d] = sum of h[other] over type-t messages into d. No ht materialization.
// Round-9 failed on aggregation structure (9 serial type-runs of avg 0.71
// records -> 9 exposed gather latencies per node-dir). Round-10 fix:
//  - CSR at (node,dir) granularity (2*Nn segments, 200K-element scan),
//    type packed in record: rec = (t<<20) | otherNode
//  - wave streams its segment 4 records at a time (4 Hbf row loads in
//    flight), t lifted to SGPR via readfirstlane, 9-way uniform switch with
//    CONSTANT-index accumulators (18 fp32 regs, no scratch), deg counts free
//  - flush bf16 Mt[16][9*128] per dir, then r9-validated MFMA (swapped
//    operands) + deg*b epilogue. No atomics anywhere in the hot path.

#define E_DIM 128
#define R_REL 9
#define TN 16        // nodes per fused block
#define MT_P 1156    // Mt pitch in ushorts
#define SCB 1024     // elements per scan block
#define NSLICE 96    // edge slices per octant in count/fill

typedef __attribute__((ext_vector_type(8))) short short8v;
typedef __attribute__((ext_vector_type(4))) float f32x4;

static __device__ __forceinline__ unsigned short f2bf(float f) {
    union { float f; unsigned u; } v; v.f = f;
    unsigned u = v.u;
    return (unsigned short)((u + 0x7FFFu + ((u >> 16) & 1u)) >> 16);
}
static __device__ __forceinline__ float bf2f(unsigned short h) {
    union { unsigned u; float f; } v; v.u = ((unsigned)h) << 16;
    return v.f;
}

// ---------- fast path ----------

__global__ __launch_bounds__(256) void h_to_bf(
    const float* __restrict__ H, unsigned short* __restrict__ Hbf, long total8)
{
    long i = (long)blockIdx.x * 256 + threadIdx.x;
    if (i >= total8) return;
    const float4* src = (const float4*)(H + i * 8);
    float4 a = src[0], b = src[1];
    short8v o;
    o[0] = (short)f2bf(a.x); o[1] = (short)f2bf(a.y);
    o[2] = (short)f2bf(a.z); o[3] = (short)f2bf(a.w);
    o[4] = (short)f2bf(b.x); o[5] = (short)f2bf(b.y);
    o[6] = (short)f2bf(b.z); o[7] = (short)f2bf(b.w);
    *(short8v*)(Hbf + i * 8) = o;
}

// Wt[rel][w][s][c][lane][j] = bf16(W[rel][k=s*32+(lane>>4)*8+j][col=w*32+c*16+(lane&15)])
__global__ __launch_bounds__(256) void w_swizzle(
    const float* __restrict__ W18, unsigned short* __restrict__ Wt)
{
    const int rel = blockIdx.x;
    const float* __restrict__ Wr = W18 + (size_t)rel * E_DIM * E_DIM;
    const int tid = threadIdx.x;
#pragma unroll
    for (int k = 0; k < 8; k++) {
        int f = tid + k * 256;            // 0..2047
        int lane = f & 63;
        int c = (f >> 6) & 1;
        int s = (f >> 7) & 3;
        int w = (f >> 9) & 3;
        int col = w * 32 + c * 16 + (lane & 15);
        int kb = s * 32 + (lane >> 4) * 8;
        short8v v;
#pragma unroll
        for (int j = 0; j < 8; j++)
            v[j] = (short)f2bf(Wr[(size_t)(kb + j) * E_DIM + col]);
        *(short8v*)(Wt + ((size_t)((((rel * 4 + w) * 4 + s) * 2 + c) * 64 + lane)) * 8) = v;
    }
}

// CSR over n2 = 2*Nn segments: seg d = fwd msgs into d, seg Nn+s = bwd into s.
// Octant-partitioned (blockIdx&7 -> node octant) for XCD-L2-local counters.
__global__ __launch_bounds__(256) void k_count8(
    const int* __restrict__ esrc, const int* __restrict__ edst,
    int* __restrict__ cnt, int ne, int Nn)
{
    const int oct = blockIdx.x & 7;
    const int slice = blockIdx.x >> 3;
    const int lo = (int)(((long long)oct * Nn) >> 3);
    const int hi = (int)(((long long)(oct + 1) * Nn) >> 3);
    for (int e = slice * 256 + threadIdx.x; e < ne; e += NSLICE * 256) {
        int s = esrc[e], d = edst[e];
        if (d >= lo && d < hi) atomicAdd(&cnt[d], 1);
        if (s >= lo && s < hi) atomicAdd(&cnt[Nn + s], 1);
    }
}

// Hierarchical scan, 3 kernels (r5-validated).
__global__ __launch_bounds__(256) void k_scan_part(
    const int* __restrict__ cnt, int* __restrict__ loc,
    int* __restrict__ bsum, int n2)
{
    __shared__ int sh[256];
    const int tid = threadIdx.x;
    const int i0 = blockIdx.x * SCB + tid * 4;
    int v0 = 0, v1 = 0, v2 = 0, v3 = 0;
    if (i0 + 3 < n2) {
        int4 v = *(const int4*)(cnt + i0);
        v0 = v.x; v1 = v.y; v2 = v.z; v3 = v.w;
    } else {
        if (i0 + 0 < n2) v0 = cnt[i0 + 0];
        if (i0 + 1 < n2) v1 = cnt[i0 + 1];
        if (i0 + 2 < n2) v2 = cnt[i0 + 2];
        if (i0 + 3 < n2) v3 = cnt[i0 + 3];
    }
    int t = v0 + v1 + v2 + v3;
    sh[tid] = t;
    __syncthreads();
    for (int o = 1; o < 256; o <<= 1) {
        int x = (tid >= o) ? sh[tid - o] : 0;
        __syncthreads();
        sh[tid] += x;
        __syncthreads();
    }
    int excl = sh[tid] - t;
    if (tid == 255) bsum[blockIdx.x] = sh[255];
    int p0 = excl, p1 = p0 + v0, p2 = p1 + v1, p3 = p2 + v2;
    if (i0 + 3 < n2) {
        *(int4*)(loc + i0) = make_int4(p0, p1, p2, p3);
    } else {
        if (i0 + 0 < n2) loc[i0 + 0] = p0;
        if (i0 + 1 < n2) loc[i0 + 1] = p1;
        if (i0 + 2 < n2) loc[i0 + 2] = p2;
        if (i0 + 3 < n2) loc[i0 + 3] = p3;
    }
}

__global__ __launch_bounds__(256) void k_scan_mid(int* __restrict__ bsum, int nb)
{
    __shared__ int sh[256];
    __shared__ int carry;
    const int tid = threadIdx.x;
    if (tid == 0) carry = 0;
    __syncthreads();
    for (int base = 0; base < nb; base += 256) {
        int i = base + tid;
        int v = (i < nb) ? bsum[i] : 0;
        sh[tid] = v;
        __syncthreads();
        for (int o = 1; o < 256; o <<= 1) {
            int x = (tid >= o) ? sh[tid - o] : 0;
            __syncthreads();
            sh[tid] += x;
            __syncthreads();
        }
        int excl = sh[tid] - v + carry;
        int total = sh[255];
        if (i < nb) bsum[i] = excl;
        __syncthreads();
        if (tid == 0) carry += total;
        __syncthreads();
    }
}

__global__ __launch_bounds__(256) void k_scan_apply(
    const int* __restrict__ loc, const int* __restrict__ bsum,
    int* __restrict__ off, int* __restrict__ cursor, int n2)
{
    const int add = bsum[blockIdx.x];
    const int i0 = blockIdx.x * SCB + threadIdx.x * 4;
    if (i0 + 3 < n2) {
        int4 v = *(const int4*)(loc + i0);
        v.x += add; v.y += add; v.z += add; v.w += add;
        *(int4*)(off + i0) = v;
        *(int4*)(cursor + i0) = v;
    } else {
#pragma unroll
        for (int j = 0; j < 4; j++)
            if (i0 + j < n2) {
                int v = loc[i0 + j] + add;
                off[i0 + j] = v;
                cursor[i0 + j] = v;
            }
    }
}

// rec = (t<<20) | otherNode  (Nn < 2^20, t < 9). Octant-partitioned.
__global__ __launch_bounds__(256) void k_fill8(
    const int* __restrict__ esrc, const int* __restrict__ edst,
    const int* __restrict__ etype, int* __restrict__ cursor,
    unsigned* __restrict__ rec, int ne, int Nn)
{
    const int oct = blockIdx.x & 7;
    const int slice = blockIdx.x >> 3;
    const int lo = (int)(((long long)oct * Nn) >> 3);
    const int hi = (int)(((long long)(oct + 1) * Nn) >> 3);
    for (int e = slice * 256 + threadIdx.x; e < ne; e += NSLICE * 256) {
        int t = etype[e], s = esrc[e], d = edst[e];
        if (d >= lo && d < hi) {
            int p = atomicAdd(&cursor[d], 1);
            rec[p] = ((unsigned)t << 20) | (unsigned)s;   // fwd msg into d
        }
        if (s >= lo && s < hi) {
            int p2 = atomicAdd(&cursor[Nn + s], 1);
            rec[p2] = ((unsigned)t << 20) | (unsigned)d;  // bwd msg into s
        }
    }
}

// Accumulate one record: t is wave-uniform (SGPR) -> uniform 9-way branch,
// constant array indices (registers, no scratch). deg counts in the switch.
#define SW_ACC(rv, vv)                                                        \
    {                                                                         \
        int _t = (rv) >> 20;                                                  \
        float _f0 = bf2f((vv).x), _f1 = bf2f((vv).y);                         \
        switch (_t) {                                                         \
        case 0: ax[0] += _f0; ay[0] += _f1; cn[0]++; break;                   \
        case 1: ax[1] += _f0; ay[1] += _f1; cn[1]++; break;                   \
        case 2: ax[2] += _f0; ay[2] += _f1; cn[2]++; break;                   \
        case 3: ax[3] += _f0; ay[3] += _f1; cn[3]++; break;                   \
        case 4: ax[4] += _f0; ay[4] += _f1; cn[4]++; break;                   \
        case 5: ax[5] += _f0; ay[5] += _f1; cn[5]++; break;                   \
        case 6: ax[6] += _f0; ay[6] += _f1; cn[6]++; break;                   \
        case 7: ax[7] += _f0; ay[7] += _f1; cn[7]++; break;                   \
        default: ax[8] += _f0; ay[8] += _f1; cn[8]++; break;                  \
        }                                                                     \
    }

// Fused aggregate+GEMM. Block = 16 nodes, 4 waves. Per direction:
//   wave w aggregates nodes w*4..w*4+3: single record loop (4-deep load
//   pipeline), SGPR-switch accumulation into 18 fp32 regs; flush bf16 to
//   Mt[node][t*128+2*lane]; barrier; MFMA acc += Mt @ W[dir] (swapped
//   operands: lane&15 = node, acc reg = 4 consecutive cols); barrier.
// Epilogue: + deg_t*b_t both dirs, single fp32 out store.
__global__ __launch_bounds__(256, 4) void fused_rgcn(
    const unsigned short* __restrict__ Hbf, const unsigned short* __restrict__ Wt,
    const float* __restrict__ B18,
    const int* __restrict__ off2, const int* __restrict__ cur2,
    const unsigned* __restrict__ rec,
    float* __restrict__ out, int Nn)
{
    __shared__ __align__(16) unsigned short Mt[TN][MT_P];
    __shared__ float degS[2][TN][R_REL];

    const int tid = threadIdx.x;
    const int lane = tid & 63;
    const int w = tid >> 6;             // wave id; col slice w*32..w*32+31
    const int lr = lane & 15;
    const int lg = lane >> 4;
    const int n0 = blockIdx.x * TN;

    const short8v* wt8 = (const short8v*)Wt;

    f32x4 acc[2];
    acc[0] = (f32x4){0.f, 0.f, 0.f, 0.f};
    acc[1] = (f32x4){0.f, 0.f, 0.f, 0.f};

#pragma unroll 1
    for (int dir = 0; dir < 2; dir++) {
        // ---- aggregation: wave w owns nodes w*4 .. w*4+3 ----
#pragma unroll 1
        for (int j = 0; j < 4; j++) {
            const int node = w * 4 + j;
            const int gnode = n0 + node;
            int st = 0, en = 0;
            if (gnode < Nn) {
                int seg = dir ? (Nn + gnode) : gnode;
                st = off2[seg];
                en = cur2[seg];
            }
            float ax[R_REL] = {0.f, 0.f, 0.f, 0.f, 0.f, 0.f, 0.f, 0.f, 0.f};
            float ay[R_REL] = {0.f, 0.f, 0.f, 0.f, 0.f, 0.f, 0.f, 0.f, 0.f};
            int cn[R_REL] = {0, 0, 0, 0, 0, 0, 0, 0, 0};

            int i = st;
            for (; i + 4 <= en; i += 4) {
                int r0 = __builtin_amdgcn_readfirstlane((int)rec[i + 0]);
                int r1 = __builtin_amdgcn_readfirstlane((int)rec[i + 1]);
                int r2 = __builtin_amdgcn_readfirstlane((int)rec[i + 2]);
                int r3 = __builtin_amdgcn_readfirstlane((int)rec[i + 3]);
                ushort2 v0 = *(const ushort2*)(Hbf + (size_t)(r0 & 0xFFFFF) * E_DIM + 2 * lane);
                ushort2 v1 = *(const ushort2*)(Hbf + (size_t)(r1 & 0xFFFFF) * E_DIM + 2 * lane);
                ushort2 v2 = *(const ushort2*)(Hbf + (size_t)(r2 & 0xFFFFF) * E_DIM + 2 * lane);
                ushort2 v3 = *(const ushort2*)(Hbf + (size_t)(r3 & 0xFFFFF) * E_DIM + 2 * lane);
                SW_ACC(r0, v0);
                SW_ACC(r1, v1);
                SW_ACC(r2, v2);
                SW_ACC(r3, v3);
            }
            for (; i < en; i++) {
                int r0 = __builtin_amdgcn_readfirstlane((int)rec[i]);
                ushort2 v0 = *(const ushort2*)(Hbf + (size_t)(r0 & 0xFFFFF) * E_DIM + 2 * lane);
                SW_ACC(r0, v0);
            }

            // Flush: lane writes 9 packed u32 (2 bf16 channels per type).
#pragma unroll
            for (int t = 0; t < R_REL; t++) {
                unsigned pk = ((unsigned)f2bf(ay[t]) << 16) | (unsigned)f2bf(ax[t]);
                *(unsigned*)((char*)&Mt[node][t * E_DIM] + lane * 4) = pk;
            }
            if (lane == 0) {
#pragma unroll
                for (int t = 0; t < R_REL; t++)
                    degS[dir][node][t] = (float)cn[t];
            }
        }
        __syncthreads();

        // ---- GEMM: acc += Mt @ W[dir group] ----
#pragma unroll 1
        for (int q = 0; q < R_REL; q++) {
            const int rel = dir * R_REL + q;
#pragma unroll
            for (int s = 0; s < 4; s++) {
                short8v b0 = wt8[(size_t)((((rel * 4 + w) * 4 + s) * 2 + 0) * 64) + lane];
                short8v b1 = wt8[(size_t)((((rel * 4 + w) * 4 + s) * 2 + 1) * 64) + lane];
                short8v a = *(const short8v*)(&Mt[lr][q * E_DIM + s * 32 + lg * 8]);
                acc[0] = __builtin_amdgcn_mfma_f32_16x16x32_bf16(b0, a, acc[0], 0, 0, 0);
                acc[1] = __builtin_amdgcn_mfma_f32_16x16x32_bf16(b1, a, acc[1], 0, 0, 0);
            }
        }
        __syncthreads();   // before next dir overwrites Mt
    }

    // ---- epilogue: bias (deg_t * b_t) + store ----
    const int gnode = n0 + lr;
    if (gnode >= Nn) return;
#pragma unroll 1
    for (int dir = 0; dir < 2; dir++) {
#pragma unroll 1
        for (int t = 0; t < R_REL; t++) {
            float dg = degS[dir][lr][t];
            if (dg != 0.f) {
                const float* brow = B18 + (size_t)(dir * R_REL + t) * E_DIM + w * 32 + lg * 4;
                float4 b0 = *(const float4*)(brow);
                float4 b1 = *(const float4*)(brow + 16);
                acc[0][0] += dg * b0.x; acc[0][1] += dg * b0.y;
                acc[0][2] += dg * b0.z; acc[0][3] += dg * b0.w;
                acc[1][0] += dg * b1.x; acc[1][1] += dg * b1.y;
                acc[1][2] += dg * b1.z; acc[1][3] += dg * b1.w;
            }
        }
    }
    float* po = out + (size_t)gnode * E_DIM + w * 32 + lg * 4;
    *(float4*)po = make_float4(acc[0][0], acc[0][1], acc[0][2], acc[0][3]);
    *(float4*)(po + 16) = make_float4(acc[1][0], acc[1][1], acc[1][2], acc[1][3]);
}

// ---------- zero-workspace fallback (round-1, validated) ----------

__global__ __launch_bounds__(128) void direct_edge(
    const int* __restrict__ esrc, const int* __restrict__ edst,
    const int* __restrict__ etype,
    const float* __restrict__ H, const float* __restrict__ W2,
    const float* __restrict__ B2, float* __restrict__ out, int ne)
{
    __shared__ float hs[E_DIM];
    __shared__ float hd[E_DIM];
    int e = blockIdx.x;
    if (e >= ne) return;
    int t = etype[e], s = esrc[e], d = edst[e];
    int c = threadIdx.x;
    hs[c] = H[(size_t)s * E_DIM + c];
    hd[c] = H[(size_t)d * E_DIM + c];
    __syncthreads();
    const float* Wf = W2 + (size_t)t * E_DIM * E_DIM;
    const float* Wb = W2 + (size_t)(t + R_REL) * E_DIM * E_DIM;
    float accf = B2[(size_t)t * E_DIM + c];
    float accb = B2[(size_t)(t + R_REL) * E_DIM + c];
#pragma unroll 8
    for (int k = 0; k < E_DIM; k++) {
        accf += hs[k] * Wf[(size_t)k * E_DIM + c];
        accb += hd[k] * Wb[(size_t)k * E_DIM + c];
    }
    atomicAdd(&out[(size_t)d * E_DIM + c], accf);
    atomicAdd(&out[(size_t)s * E_DIM + c], accb);
}

extern "C" void kernel_launch(void* const* d_in, const int* in_sizes, int n_in,
                              void* d_out, int out_size, void* d_ws, size_t ws_size,
                              hipStream_t stream) {
    const int* edge_index = (const int*)d_in[0];   // [2][NE]
    const int* edge_type  = (const int*)d_in[1];   // [NE]
    const float* emb      = (const float*)d_in[2]; // [N][128]
    const float* weights  = (const float*)d_in[3]; // [L][18][128][128]
    const float* biases   = (const float*)d_in[4]; // [L][18][128]
    float* out = (float*)d_out;

    const int NE = in_sizes[1];
    const int Nn = in_sizes[2] / E_DIM;
    const int L  = in_sizes[3] / (2 * R_REL * E_DIM * E_DIM);

    const float* W2 = weights + (size_t)(L - 1) * 2 * R_REL * E_DIM * E_DIM;
    const float* B2 = biases  + (size_t)(L - 1) * 2 * R_REL * E_DIM;

    const int* esrc = edge_index;
    const int* edst = edge_index + NE;

    const int n2 = 2 * Nn;                         // (node,dir) segments
    const int nb2 = (n2 + SCB - 1) / SCB;

    auto al = [](size_t x) { return (x + 255) & ~(size_t)255; };
    const size_t hbfBytes = al((size_t)Nn * E_DIM * 2);
    const size_t wtBytes  = al((size_t)2 * R_REL * E_DIM * E_DIM * 2);
    const size_t offBytes = al((size_t)n2 * 4);
    const size_t curBytes = al((size_t)n2 * 4);
    const size_t recBytes = al((size_t)2 * NE * 4);
    const size_t bsBytes  = al((size_t)nb2 * 4);
    const size_t need = hbfBytes + wtBytes + offBytes + curBytes + recBytes + bsBytes;

    if (ws_size >= need && Nn < (1 << 20)) {
        char* p = (char*)d_ws;
        unsigned short* Hbf = (unsigned short*)p;        p += hbfBytes;
        unsigned short* Wt  = (unsigned short*)p;        p += wtBytes;
        int* off2           = (int*)p;                   p += offBytes;
        int* cur2           = (int*)p;                   p += curBytes;
        unsigned* rec       = (unsigned*)p;              p += recBytes;
        int* bsum           = (int*)p;

        const long total8 = (long)Nn * (E_DIM / 8);
        h_to_bf<<<(int)((total8 + 255) / 256), 256, 0, stream>>>(emb, Hbf, total8);
        w_swizzle<<<2 * R_REL, 256, 0, stream>>>(W2, Wt);

        hipMemsetAsync(off2, 0, (size_t)n2 * 4, stream);
        k_count8<<<8 * NSLICE, 256, 0, stream>>>(esrc, edst, off2, NE, Nn);
        k_scan_part<<<nb2, 256, 0, stream>>>(off2, cur2, bsum, n2);
        k_scan_mid<<<1, 256, 0, stream>>>(bsum, nb2);
        k_scan_apply<<<nb2, 256, 0, stream>>>(cur2, bsum, off2, cur2, n2);
        k_fill8<<<8 * NSLICE, 256, 0, stream>>>(esrc, edst, edge_type,
                                                cur2, rec, NE, Nn);

        fused_rgcn<<<(Nn + TN - 1) / TN, 256, 0, stream>>>(
            Hbf, Wt, B2, off2, cur2, rec, out, Nn);
        return;
    }

    // Fallback: direct per-edge GEMV with atomics.
    hipMemsetAsync(d_out, 0, (size_t)Nn * E_DIM * sizeof(float), stream);
    direct_edge<<<NE, 128, 0, stream>>>(esrc, edst, edge_type, emb, W2, B2, out, NE);
}